// Round 1
// baseline (307.021 us; speedup 1.0000x reference)
//
#include <hip/hip_runtime.h>
#include <math.h>

#define NB 37
#define BB 4
#define CC 2
#define FF 1025
#define TT 2048
#define EE 128
#define DD 260
#define DPAD 264
#define EPSF 1e-5f

// ---------------------------------------------------------------------------
// Kernel 1: per-band prep.
// A[e,d] = ln_gamma[d] * mask[d] * (g[e]*v[e,d]/||v[e]||)
// stored compact+transposed: AT[n][dc][e], dc = compact d index (c*2bw + 2w + ri),
// zero-padded to DPAD rows. Also s1[e] = sum_d A[e,d], s2p[e] = sum_d beta*m*W + bias.
// ---------------------------------------------------------------------------
__global__ __launch_bounds__(256) void prep_kernel(
    const float* __restrict__ gamma, const float* __restrict__ beta,
    const float* __restrict__ v, const float* __restrict__ g,
    const float* __restrict__ bias, const int* __restrict__ bwidth,
    float* __restrict__ AT, float* __restrict__ s1o, float* __restrict__ s2o)
{
    int n   = blockIdx.x;
    int bw  = bwidth[n];
    int Deff = 4 * bw;
    int twobw = 2 * bw;
    int tid = threadIdx.x;

    __shared__ float part[256];
    __shared__ float vn[EE];

    // ||v[e]|| : 2 threads per e
    {
        int e = tid >> 1, half = tid & 1;
        const float* vp = v + (size_t)(n * EE + e) * DD;
        float s = 0.f;
        for (int d = half; d < DD; d += 2) { float val = vp[d]; s += val * val; }
        part[tid] = s;
    }
    __syncthreads();
    if (tid < EE) vn[tid] = sqrtf(part[2 * tid] + part[2 * tid + 1]);
    __syncthreads();

    // fill AT[n][dc][e]
    for (int idx = tid; idx < DPAD * EE; idx += 256) {
        int dc = idx >> 7;
        int e  = idx & 127;
        float val = 0.f;
        if (dc < Deff) {
            int c = dc / twobw;
            int rem = dc - c * twobw;      // 2w + ri
            int d = c * (2 * 65) + rem;    // full-d index
            float W = g[n * EE + e] * v[(size_t)(n * EE + e) * DD + d] / vn[e];
            val = gamma[n * DD + d] * W;
        }
        AT[((size_t)n * DPAD + dc) * EE + e] = val;
    }

    // s1, s2p
    if (tid < EE) {
        int e = tid;
        float ge = g[n * EE + e], vne = vn[e];
        const float* vp = v + (size_t)(n * EE + e) * DD;
        float s1 = 0.f, s2 = 0.f;
        for (int dc = 0; dc < Deff; ++dc) {
            int c = dc / twobw;
            int rem = dc - c * twobw;
            int d = c * 130 + rem;
            float W = ge * vp[d] / vne;
            s1 += gamma[n * DD + d] * W;
            s2 += beta[n * DD + d] * W;
        }
        s1o[n * EE + e] = s1;
        s2o[n * EE + e] = s2 + bias[n * EE + e];
    }
}

// ---------------------------------------------------------------------------
// Kernel 2: per-(b,n,t) masked mean / rsqrt(var+eps).
// grid = B*NB*(T/256), one thread per t. Coalesced float2 reads along t.
// ---------------------------------------------------------------------------
__global__ __launch_bounds__(256) void stats_kernel(
    const float* __restrict__ x, const int* __restrict__ bstart,
    const int* __restrict__ bwidth,
    float* __restrict__ meanArr, float* __restrict__ rsArr)
{
    int bid = blockIdx.x;
    int tc  = bid & 7;                 // T/256 = 8
    int n   = (bid >> 3) % NB;
    int b   = bid / (8 * NB);
    int t   = tc * 256 + threadIdx.x;
    int f0  = bstart[n];
    int bw  = bwidth[n];

    float sum = 0.f, sq = 0.f;
    for (int c = 0; c < CC; ++c) {
        const float* base = x + ((size_t)((b * CC + c) * FF + f0)) * (TT * 2) + (size_t)t * 2;
        for (int w = 0; w < bw; ++w) {
            float2 p = *reinterpret_cast<const float2*>(base + (size_t)w * (TT * 2));
            sum += p.x + p.y;
            sq  = fmaf(p.x, p.x, sq);
            sq  = fmaf(p.y, p.y, sq);
        }
    }
    float inv  = 1.f / (float)(4 * bw);
    float mean = sum * inv;
    float var  = sq * inv - mean * mean;
    float rs   = rsqrtf(var + EPSF);
    size_t o = ((size_t)(b * NB + n)) * TT + t;
    meanArr[o] = mean;
    rsArr[o]   = rs;
}

// ---------------------------------------------------------------------------
// Kernel 3: per-(b,n) GEMM  z[t,e] = rs_t*(X[t,:]·A[:,e] - mean_t*s1[e]) + s2p[e]
// 128 t x 128 e tile per block, 256 threads, K chunks of 8 staged in LDS.
// Thread (ti=tid&15, ei=tid>>4) owns t in {ti+16*it}, e in {ei*8+j}.
// ---------------------------------------------------------------------------
__global__ __launch_bounds__(256) void gemm_kernel(
    const float* __restrict__ x, const int* __restrict__ bstart,
    const int* __restrict__ bwidth,
    const float* __restrict__ AT, const float* __restrict__ s1a,
    const float* __restrict__ s2a,
    const float* __restrict__ meanArr, const float* __restrict__ rsArr,
    float* __restrict__ out)
{
    int bid = blockIdx.x;
    int tt  = bid & 15;                // T/128 = 16
    int n   = (bid >> 4) % NB;
    int b   = bid / (16 * NB);
    int t0  = tt * 128;
    int f0  = bstart[n];
    int bw  = bwidth[n];
    int npairs  = 2 * bw;
    int Deff    = 4 * bw;
    int nChunks = (Deff + 7) >> 3;

    __shared__ float Xs[8][128];
    __shared__ float As[8][128];
    __shared__ unsigned offL[132];
    __shared__ float ms[128], rss[128];

    int tid = threadIdx.x;
    if (tid < 132) {
        unsigned off = 0xFFFFFFFFu;
        if (tid < npairs) {
            int c = tid / bw;
            int w = tid - c * bw;
            off = (unsigned)((b * CC + c) * FF + f0 + w) * (TT * 2);
        }
        offL[tid] = off;
    }
    if (tid < 128) {
        size_t o = ((size_t)(b * NB + n)) * TT + t0 + tid;
        ms[tid]  = meanArr[o];
        rss[tid] = rsArr[o];
    }
    __syncthreads();

    int ti = tid & 15;
    int ei = tid >> 4;

    float acc[8][8];
    #pragma unroll
    for (int i = 0; i < 8; ++i)
        #pragma unroll
        for (int j = 0; j < 8; ++j) acc[i][j] = 0.f;

    const float* ATn = AT + (size_t)n * DPAD * EE;

    for (int ch = 0; ch < nChunks; ++ch) {
        int dBase = ch * 8;
        // stage X chunk: rows dBase..dBase+7 (4 float2-pairs) x 128 t
        #pragma unroll
        for (int rep = 0; rep < 2; ++rep) {
            int i = rep * 256 + tid;
            int p = i >> 7;            // 0..3
            int t = i & 127;
            unsigned off = offL[(dBase >> 1) + p];
            float2 val = make_float2(0.f, 0.f);
            if (off != 0xFFFFFFFFu)
                val = *reinterpret_cast<const float2*>(x + (size_t)off + (size_t)(t0 + t) * 2);
            Xs[2 * p][t]     = val.x;
            Xs[2 * p + 1][t] = val.y;
        }
        // stage A chunk: 8 x 128 contiguous
        {
            float4 av = *reinterpret_cast<const float4*>(ATn + (size_t)dBase * EE + tid * 4);
            *reinterpret_cast<float4*>(&As[0][0] + tid * 4) = av;
        }
        __syncthreads();

        #pragma unroll
        for (int kk = 0; kk < 8; ++kk) {
            float xr[8];
            #pragma unroll
            for (int it = 0; it < 8; ++it) xr[it] = Xs[kk][ti + 16 * it];
            float4 a0 = *reinterpret_cast<const float4*>(&As[kk][ei * 8]);
            float4 a1 = *reinterpret_cast<const float4*>(&As[kk][ei * 8 + 4]);
            float ar[8] = {a0.x, a0.y, a0.z, a0.w, a1.x, a1.y, a1.z, a1.w};
            #pragma unroll
            for (int it = 0; it < 8; ++it)
                #pragma unroll
                for (int j = 0; j < 8; ++j)
                    acc[it][j] = fmaf(xr[it], ar[j], acc[it][j]);
        }
        __syncthreads();
    }

    // epilogue
    float s1r[8], s2r[8];
    #pragma unroll
    for (int j = 0; j < 8; ++j) {
        s1r[j] = s1a[n * EE + ei * 8 + j];
        s2r[j] = s2a[n * EE + ei * 8 + j];
    }
    #pragma unroll
    for (int it = 0; it < 8; ++it) {
        int t = ti + 16 * it;
        float m = ms[t], r = rss[t];
        float4 z0, z1;
        z0.x = fmaf(r, acc[it][0] - m * s1r[0], s2r[0]);
        z0.y = fmaf(r, acc[it][1] - m * s1r[1], s2r[1]);
        z0.z = fmaf(r, acc[it][2] - m * s1r[2], s2r[2]);
        z0.w = fmaf(r, acc[it][3] - m * s1r[3], s2r[3]);
        z1.x = fmaf(r, acc[it][4] - m * s1r[4], s2r[4]);
        z1.y = fmaf(r, acc[it][5] - m * s1r[5], s2r[5]);
        z1.z = fmaf(r, acc[it][6] - m * s1r[6], s2r[6]);
        z1.w = fmaf(r, acc[it][7] - m * s1r[7], s2r[7]);
        float* op = out + (((size_t)(b * NB + n)) * TT + t0 + t) * EE + ei * 8;
        *reinterpret_cast<float4*>(op)     = z0;
        *reinterpret_cast<float4*>(op + 4) = z1;
    }
}

// ---------------------------------------------------------------------------
extern "C" void kernel_launch(void* const* d_in, const int* in_sizes, int n_in,
                              void* d_out, int out_size, void* d_ws, size_t ws_size,
                              hipStream_t stream)
{
    const float* x      = (const float*)d_in[0];
    const float* gamma  = (const float*)d_in[1];
    const float* beta   = (const float*)d_in[2];
    const float* v      = (const float*)d_in[3];
    const float* g      = (const float*)d_in[4];
    const float* bias   = (const float*)d_in[5];
    const int*   bstart = (const int*)d_in[6];
    const int*   bwidth = (const int*)d_in[7];
    float* out = (float*)d_out;

    float* AT      = (float*)d_ws;                       // 37*264*128
    float* s1      = AT + (size_t)NB * DPAD * EE;        // 4736
    float* s2p     = s1 + NB * EE;                       // 4736
    float* meanArr = s2p + NB * EE;                      // 303104
    float* rsArr   = meanArr + (size_t)BB * NB * TT;     // 303104

    prep_kernel<<<NB, 256, 0, stream>>>(gamma, beta, v, g, bias, bwidth, AT, s1, s2p);
    stats_kernel<<<BB * NB * (TT / 256), 256, 0, stream>>>(x, bstart, bwidth, meanArr, rsArr);
    gemm_kernel<<<BB * NB * (TT / 128), 256, 0, stream>>>(x, bstart, bwidth, AT, s1, s2p,
                                                          meanArr, rsArr, out);
}

// Round 2
// 179.874 us; speedup vs baseline: 1.7069x; 1.7069x over previous
//
#include <hip/hip_runtime.h>
#include <math.h>

#define NB 37
#define BB 4
#define CC 2
#define FF 1025
#define TT 2048
#define EE 128
#define DD 260
#define EPSF 1e-5f
#define CHS 9           // max K chunks of 32 (Kpad<=288)
#define XROW 40         // padded LDS row in bf16 elems (80B, 16B-aligned, 20-bank stride)

typedef short s16x8 __attribute__((ext_vector_type(8)));
typedef float f32x4 __attribute__((ext_vector_type(4)));

__device__ __forceinline__ unsigned short f2bf(float f) {
    unsigned u = __builtin_bit_cast(unsigned, f);
    unsigned r = (u + 0x7FFFu + ((u >> 16) & 1u)) >> 16;
    return (unsigned short)r;
}

// ---------------------------------------------------------------------------
// Kernel 1: per-band prep. Folds weight-norm * gamma into bf16 A, laid out as
// ATg[n][ch][e][32k] (K-chunk tiles, k contiguous) for coalesced GEMM staging.
// Also s1[e] = sum_d A[e,d] (fp32), s2p[e] = sum_d beta_d*W[e,d] + bias[e].
// ---------------------------------------------------------------------------
__global__ __launch_bounds__(256) void prep_kernel(
    const float* __restrict__ gamma, const float* __restrict__ beta,
    const float* __restrict__ v, const float* __restrict__ g,
    const float* __restrict__ bias, const int* __restrict__ bwidth,
    unsigned short* __restrict__ ATg, float* __restrict__ s1o, float* __restrict__ s2o)
{
    int n    = blockIdx.x;
    int bw   = bwidth[n];
    int Deff = 4 * bw;
    int twobw = 2 * bw;
    int tid  = threadIdx.x;

    __shared__ float part[256];
    __shared__ float vn[EE];

    {   // ||v[e]||, 2 threads per e
        int e = tid >> 1, half = tid & 1;
        const float* vp = v + (size_t)(n * EE + e) * DD;
        float s = 0.f;
        for (int d = half; d < DD; d += 2) { float val = vp[d]; s += val * val; }
        part[tid] = s;
    }
    __syncthreads();
    if (tid < EE) vn[tid] = sqrtf(part[2 * tid] + part[2 * tid + 1]);
    __syncthreads();

    int nCh = (Deff + 31) >> 5;
    for (int idx = tid; idx < nCh * EE * 32; idx += 256) {
        int kk = idx & 31;
        int e  = (idx >> 5) & 127;
        int ch = idx >> 12;
        int k  = ch * 32 + kk;
        float val = 0.f;
        if (k < Deff) {
            int c   = (k >= twobw) ? 1 : 0;
            int rem = k - c * twobw;
            int d   = c * 130 + rem;
            float W = g[n * EE + e] * v[(size_t)(n * EE + e) * DD + d] / vn[e];
            val = gamma[n * DD + d] * W;
        }
        ATg[((size_t)n * CHS + ch) * (EE * 32) + (e * 32 + kk)] = f2bf(val);
    }

    if (tid < EE) {
        int e = tid;
        float ge = g[n * EE + e], vne = vn[e];
        const float* vp = v + (size_t)(n * EE + e) * DD;
        float s1 = 0.f, s2 = 0.f;
        for (int dc = 0; dc < Deff; ++dc) {
            int c   = (dc >= twobw) ? 1 : 0;
            int rem = dc - c * twobw;
            int d   = c * 130 + rem;
            float W = ge * vp[d] / vne;
            s1 += gamma[n * DD + d] * W;
            s2 += beta[n * DD + d] * W;
        }
        s1o[n * EE + e] = s1;
        s2o[n * EE + e] = s2 + bias[n * EE + e];
    }
}

// ---------------------------------------------------------------------------
// Kernel 2: fused stats + bf16 MFMA GEMM + epilogue.
// Block tile: 128 t x 128 e, 4 waves (64t x 64e each), K chunks of 32.
// Stats (fp32 sum/sumsq per t) accumulate during X staging; finalized before
// the epilogue, which applies z = rs*(acc - mean*s1) + s2.
// ---------------------------------------------------------------------------
__global__ __launch_bounds__(256) void fused_kernel(
    const float* __restrict__ x, const int* __restrict__ bstart,
    const int* __restrict__ bwidth,
    const unsigned short* __restrict__ ATg, const float* __restrict__ s1a,
    const float* __restrict__ s2a, float* __restrict__ out)
{
    int bid = blockIdx.x;
    int tt  = bid & 15;                 // T/128 = 16, fastest -> same-n blocks adjacent
    int n   = (bid >> 4) % NB;
    int b   = bid / (16 * NB);
    int t0  = tt * 128;
    int f0  = bstart[n];
    int bw  = bwidth[n];
    int nPairs = 2 * bw;
    int Deff   = 4 * bw;
    int nCh    = (Deff + 31) >> 5;

    int tid  = threadIdx.x;
    int lane = tid & 63;
    int l15  = lane & 15;
    int ksub = lane >> 4;               // 0..3 -> k byte offset ksub*16

    __shared__ __align__(16) unsigned short Xs[128 * XROW];
    __shared__ __align__(16) unsigned short As[128 * XROW];
    __shared__ unsigned offP[160];
    __shared__ float psum[256], psq[256], ms[128], rss[128];

    // per-pair global float offsets (t term excluded); pad -> sentinel
    for (int p = tid; p < 160; p += 256) {
        unsigned off = 0xFFFFFFFFu;
        if (p < nPairs) {
            int c = (p >= bw) ? 1 : 0;
            int w = p - c * bw;
            off = (unsigned)(((b * CC + c) * FF + f0 + w) * (TT * 2));
        }
        offP[p] = off;
    }
    __syncthreads();

    int tloc = tid & 127;               // staging t (fixed per thread)
    int kc8a = tid >> 7;                // staging k-slice: kc8a and kc8a+2
    float sAcc = 0.f, qAcc = 0.f;

    int wv    = tid >> 6;
    int twave = (wv >> 1) * 64;
    int ewave = (wv & 1) * 64;

    f32x4 acc[4][4];
    #pragma unroll
    for (int mi = 0; mi < 4; ++mi)
        #pragma unroll
        for (int ni = 0; ni < 4; ++ni)
            acc[mi][ni] = (f32x4){0.f, 0.f, 0.f, 0.f};

    const unsigned short* Abase = ATg + (size_t)n * CHS * (EE * 32);

    for (int ch = 0; ch < nCh; ++ch) {
        // ---- load X slices to regs (fp32), accumulate stats, convert bf16
        unsigned short xv[2][8];
        #pragma unroll
        for (int s = 0; s < 2; ++s) {
            int kc8   = kc8a + 2 * s;
            int pbase = ch * 16 + kc8 * 4;
            #pragma unroll
            for (int j = 0; j < 4; ++j) {
                unsigned off = offP[pbase + j];
                float2 val = make_float2(0.f, 0.f);
                if (off != 0xFFFFFFFFu)
                    val = *reinterpret_cast<const float2*>(
                        x + (size_t)off + (size_t)(t0 + tloc) * 2);
                sAcc += val.x + val.y;
                qAcc = fmaf(val.x, val.x, qAcc);
                qAcc = fmaf(val.y, val.y, qAcc);
                xv[s][2 * j]     = f2bf(val.x);
                xv[s][2 * j + 1] = f2bf(val.y);
            }
        }
        // ---- load A chunk to regs (16B x 2 per thread, contiguous 8KB)
        const s16x8* Ag = reinterpret_cast<const s16x8*>(Abase + (size_t)ch * (EE * 32));
        s16x8 av0 = Ag[tid];
        s16x8 av1 = Ag[tid + 256];

        __syncthreads();   // prev chunk's frag reads complete

        // ---- LDS writes (padded rows: conflict-free b128)
        #pragma unroll
        for (int s = 0; s < 2; ++s) {
            int kc8 = kc8a + 2 * s;
            *reinterpret_cast<s16x8*>(&Xs[tloc * XROW + kc8 * 8]) =
                *reinterpret_cast<const s16x8*>(&xv[s][0]);
        }
        {
            int e0 = tid >> 2, kc = tid & 3;
            *reinterpret_cast<s16x8*>(&As[e0 * XROW + kc * 8]) = av0;
            *reinterpret_cast<s16x8*>(&As[(64 + e0) * XROW + kc * 8]) = av1;
        }
        __syncthreads();   // tile ready

        // ---- fragments + MFMA
        s16x8 af[4], bfr[4];
        #pragma unroll
        for (int mi = 0; mi < 4; ++mi)
            af[mi] = *reinterpret_cast<const s16x8*>(
                &Xs[(twave + mi * 16 + l15) * XROW + ksub * 8]);
        #pragma unroll
        for (int ni = 0; ni < 4; ++ni)
            bfr[ni] = *reinterpret_cast<const s16x8*>(
                &As[(ewave + ni * 16 + l15) * XROW + ksub * 8]);
        #pragma unroll
        for (int mi = 0; mi < 4; ++mi)
            #pragma unroll
            for (int ni = 0; ni < 4; ++ni)
                acc[mi][ni] = __builtin_amdgcn_mfma_f32_16x16x32_bf16(
                    af[mi], bfr[ni], acc[mi][ni], 0, 0, 0);
    }

    // ---- finalize stats
    psum[tid] = sAcc;
    psq[tid]  = qAcc;
    __syncthreads();
    if (tid < 128) {
        float s = psum[tid] + psum[tid + 128];
        float q = psq[tid] + psq[tid + 128];
        float inv = 1.f / (float)Deff;
        float mean = s * inv;
        float var  = q * inv - mean * mean;
        ms[tid]  = mean;
        rss[tid] = rsqrtf(var + EPSF);
    }
    __syncthreads();

    // ---- epilogue: z = rs*(acc - mean*s1) + s2
    float s1r[4], s2r[4];
    #pragma unroll
    for (int ni = 0; ni < 4; ++ni) {
        int e = ewave + ni * 16 + l15;
        s1r[ni] = s1a[n * EE + e];
        s2r[ni] = s2a[n * EE + e];
    }
    int rbase = ksub * 4;
    size_t outRow = ((size_t)(b * NB + n)) * TT + t0;
    #pragma unroll
    for (int mi = 0; mi < 4; ++mi) {
        #pragma unroll
        for (int j = 0; j < 4; ++j) {
            int t = twave + mi * 16 + rbase + j;
            float m = ms[t], r = rss[t];
            float* op = out + (outRow + t) * EE;
            #pragma unroll
            for (int ni = 0; ni < 4; ++ni) {
                float zv = fmaf(r, acc[mi][ni][j] - m * s1r[ni], s2r[ni]);
                op[ewave + ni * 16 + l15] = zv;
            }
        }
    }
}

// ---------------------------------------------------------------------------
extern "C" void kernel_launch(void* const* d_in, const int* in_sizes, int n_in,
                              void* d_out, int out_size, void* d_ws, size_t ws_size,
                              hipStream_t stream)
{
    const float* x      = (const float*)d_in[0];
    const float* gamma  = (const float*)d_in[1];
    const float* beta   = (const float*)d_in[2];
    const float* v      = (const float*)d_in[3];
    const float* g      = (const float*)d_in[4];
    const float* bias   = (const float*)d_in[5];
    const int*   bstart = (const int*)d_in[6];
    const int*   bwidth = (const int*)d_in[7];
    float* out = (float*)d_out;

    unsigned short* ATg = (unsigned short*)d_ws;                 // 37*9*128*32 bf16
    float* s1  = (float*)(ATg + (size_t)NB * CHS * EE * 32);     // 37*128 f32
    float* s2p = s1 + NB * EE;                                   // 37*128 f32

    prep_kernel<<<NB, 256, 0, stream>>>(gamma, beta, v, g, bias, bwidth, ATg, s1, s2p);
    fused_kernel<<<BB * NB * 16, 256, 0, stream>>>(x, bstart, bwidth, ATg, s1, s2p, out);
}

// Round 3
// 80.305 us; speedup vs baseline: 3.8232x; 2.2399x over previous
//
#include <hip/hip_runtime.h>
#include <math.h>

#define NB 37
#define BB 4
#define CC 2
#define FF 1025
#define TT 2048
#define EE 128
#define DD 260
#define EPSF 1e-5f
#define CHS 9           // max K chunks of 32 (Kpad<=288)
#define XROW 40         // padded LDS row in bf16 elems (80B, 16B-aligned, 20-bank stride)

typedef short s16x8 __attribute__((ext_vector_type(8)));
typedef float f32x4 __attribute__((ext_vector_type(4)));

__device__ __forceinline__ unsigned short f2bf(float f) {
    unsigned u = __builtin_bit_cast(unsigned, f);
    unsigned r = (u + 0x7FFFu + ((u >> 16) & 1u)) >> 16;
    return (unsigned short)r;
}

// ---------------------------------------------------------------------------
// Kernel 1: per-band prep, latency-optimized.
// grid = NB*16 blocks; each block owns 8 e-rows of band n. One 32-lane group
// per e: coalesced vnorm reduce, then per-chunk fill of bf16 A with in-register
// s1/s2 partials, butterfly-reduced at the end.
// A[e,k] = gamma[d(k)] * g[e]*v[e,d(k)]/||v[e]||, ATg layout [n][ch][e][32k].
// ---------------------------------------------------------------------------
__global__ __launch_bounds__(256) void prep_kernel(
    const float* __restrict__ gamma, const float* __restrict__ beta,
    const float* __restrict__ v, const float* __restrict__ g,
    const float* __restrict__ bias, const int* __restrict__ bwidth,
    unsigned short* __restrict__ ATg, float* __restrict__ s1o, float* __restrict__ s2o)
{
    int bid = blockIdx.x;
    int n   = bid >> 4;
    int eg  = bid & 15;
    int tid = threadIdx.x;
    int el  = tid >> 5;          // 0..7
    int kk  = tid & 31;
    int e   = eg * 8 + el;

    int bw    = bwidth[n];
    int Deff  = 4 * bw;
    int twobw = 2 * bw;
    int nCh   = (Deff + 31) >> 5;

    const float* vp = v + (size_t)(n * EE + e) * DD;

    // ---- ||v[e]||^2 : coalesced strided loads + butterfly reduce
    float sq = 0.f;
    for (int d = kk; d < DD; d += 32) { float val = vp[d]; sq = fmaf(val, val, sq); }
    #pragma unroll
    for (int m = 16; m >= 1; m >>= 1) sq += __shfl_xor(sq, m);

    float rv = g[n * EE + e] * rsqrtf(sq);   // g/||v||  (vnorm>0 given data)

    // ---- fill ATg + s1/s2 partials
    float s1 = 0.f, s2 = 0.f;
    unsigned short* Abase = ATg + (size_t)n * CHS * (EE * 32) + e * 32 + kk;
    for (int ch = 0; ch < nCh; ++ch) {
        int k = ch * 32 + kk;
        float a = 0.f;
        if (k < Deff) {
            int d = (k >= twobw) ? (130 + k - twobw) : k;
            float W = rv * vp[d];
            a = gamma[n * DD + d] * W;
            s1 += a;
            s2 = fmaf(beta[n * DD + d], W, s2);
        }
        Abase[(size_t)ch * (EE * 32)] = f2bf(a);
    }
    #pragma unroll
    for (int m = 16; m >= 1; m >>= 1) { s1 += __shfl_xor(s1, m); s2 += __shfl_xor(s2, m); }
    if (kk == 0) {
        s1o[n * EE + e] = s1;
        s2o[n * EE + e] = s2 + bias[n * EE + e];
    }
}

// ---------------------------------------------------------------------------
// Kernel 2: fused stats + bf16 MFMA GEMM + epilogue.
// Block tile: 128 t x 128 e, 4 waves (64t x 64e each), K chunks of 32.
// Stats (fp32 sum/sumsq per t) accumulate during X staging; finalized before
// the epilogue, which applies z = rs*(acc - mean*s1) + s2.
// ---------------------------------------------------------------------------
__global__ __launch_bounds__(256) void fused_kernel(
    const float* __restrict__ x, const int* __restrict__ bstart,
    const int* __restrict__ bwidth,
    const unsigned short* __restrict__ ATg, const float* __restrict__ s1a,
    const float* __restrict__ s2a, float* __restrict__ out)
{
    int bid = blockIdx.x;
    int tt  = bid & 15;                 // T/128 = 16, fastest -> same-n blocks adjacent
    int n   = (bid >> 4) % NB;
    int b   = bid / (16 * NB);
    int t0  = tt * 128;
    int f0  = bstart[n];
    int bw  = bwidth[n];
    int nPairs = 2 * bw;
    int Deff   = 4 * bw;
    int nCh    = (Deff + 31) >> 5;

    int tid  = threadIdx.x;
    int lane = tid & 63;
    int l15  = lane & 15;
    int ksub = lane >> 4;               // 0..3 -> k byte offset ksub*16

    __shared__ __align__(16) unsigned short Xs[128 * XROW];
    __shared__ __align__(16) unsigned short As[128 * XROW];
    __shared__ unsigned offP[160];
    __shared__ float psum[256], psq[256], ms[128], rss[128];

    // per-pair global float offsets (t term excluded); pad -> sentinel
    for (int p = tid; p < 160; p += 256) {
        unsigned off = 0xFFFFFFFFu;
        if (p < nPairs) {
            int c = (p >= bw) ? 1 : 0;
            int w = p - c * bw;
            off = (unsigned)(((b * CC + c) * FF + f0 + w) * (TT * 2));
        }
        offP[p] = off;
    }
    __syncthreads();

    int tloc = tid & 127;               // staging t (fixed per thread)
    int kc8a = tid >> 7;                // staging k-slice: kc8a and kc8a+2
    float sAcc = 0.f, qAcc = 0.f;

    int wv    = tid >> 6;
    int twave = (wv >> 1) * 64;
    int ewave = (wv & 1) * 64;

    f32x4 acc[4][4];
    #pragma unroll
    for (int mi = 0; mi < 4; ++mi)
        #pragma unroll
        for (int ni = 0; ni < 4; ++ni)
            acc[mi][ni] = (f32x4){0.f, 0.f, 0.f, 0.f};

    const unsigned short* Abase = ATg + (size_t)n * CHS * (EE * 32);

    for (int ch = 0; ch < nCh; ++ch) {
        // ---- load X slices to regs (fp32), accumulate stats, convert bf16
        unsigned short xv[2][8];
        #pragma unroll
        for (int s = 0; s < 2; ++s) {
            int kc8   = kc8a + 2 * s;
            int pbase = ch * 16 + kc8 * 4;
            #pragma unroll
            for (int j = 0; j < 4; ++j) {
                unsigned off = offP[pbase + j];
                float2 val = make_float2(0.f, 0.f);
                if (off != 0xFFFFFFFFu)
                    val = *reinterpret_cast<const float2*>(
                        x + (size_t)off + (size_t)(t0 + tloc) * 2);
                sAcc += val.x + val.y;
                qAcc = fmaf(val.x, val.x, qAcc);
                qAcc = fmaf(val.y, val.y, qAcc);
                xv[s][2 * j]     = f2bf(val.x);
                xv[s][2 * j + 1] = f2bf(val.y);
            }
        }
        // ---- load A chunk to regs (16B x 2 per thread, contiguous 8KB)
        const s16x8* Ag = reinterpret_cast<const s16x8*>(Abase + (size_t)ch * (EE * 32));
        s16x8 av0 = Ag[tid];
        s16x8 av1 = Ag[tid + 256];

        __syncthreads();   // prev chunk's frag reads complete

        // ---- LDS writes (padded rows: conflict-free b128)
        #pragma unroll
        for (int s = 0; s < 2; ++s) {
            int kc8 = kc8a + 2 * s;
            *reinterpret_cast<s16x8*>(&Xs[tloc * XROW + kc8 * 8]) =
                *reinterpret_cast<const s16x8*>(&xv[s][0]);
        }
        {
            int e0 = tid >> 2, kc = tid & 3;
            *reinterpret_cast<s16x8*>(&As[e0 * XROW + kc * 8]) = av0;
            *reinterpret_cast<s16x8*>(&As[(64 + e0) * XROW + kc * 8]) = av1;
        }
        __syncthreads();   // tile ready

        // ---- fragments + MFMA
        s16x8 af[4], bfr[4];
        #pragma unroll
        for (int mi = 0; mi < 4; ++mi)
            af[mi] = *reinterpret_cast<const s16x8*>(
                &Xs[(twave + mi * 16 + l15) * XROW + ksub * 8]);
        #pragma unroll
        for (int ni = 0; ni < 4; ++ni)
            bfr[ni] = *reinterpret_cast<const s16x8*>(
                &As[(ewave + ni * 16 + l15) * XROW + ksub * 8]);
        #pragma unroll
        for (int mi = 0; mi < 4; ++mi)
            #pragma unroll
            for (int ni = 0; ni < 4; ++ni)
                acc[mi][ni] = __builtin_amdgcn_mfma_f32_16x16x32_bf16(
                    af[mi], bfr[ni], acc[mi][ni], 0, 0, 0);
    }

    // ---- finalize stats
    psum[tid] = sAcc;
    psq[tid]  = qAcc;
    __syncthreads();
    if (tid < 128) {
        float s = psum[tid] + psum[tid + 128];
        float q = psq[tid] + psq[tid + 128];
        float inv = 1.f / (float)Deff;
        float mean = s * inv;
        float var  = q * inv - mean * mean;
        ms[tid]  = mean;
        rss[tid] = rsqrtf(var + EPSF);
    }
    __syncthreads();

    // ---- epilogue: z = rs*(acc - mean*s1) + s2
    float s1r[4], s2r[4];
    #pragma unroll
    for (int ni = 0; ni < 4; ++ni) {
        int e = ewave + ni * 16 + l15;
        s1r[ni] = s1a[n * EE + e];
        s2r[ni] = s2a[n * EE + e];
    }
    int rbase = ksub * 4;
    size_t outRow = ((size_t)(b * NB + n)) * TT + t0;
    #pragma unroll
    for (int mi = 0; mi < 4; ++mi) {
        #pragma unroll
        for (int j = 0; j < 4; ++j) {
            int t = twave + mi * 16 + rbase + j;
            float m = ms[t], r = rss[t];
            float* op = out + (outRow + t) * EE;
            #pragma unroll
            for (int ni = 0; ni < 4; ++ni) {
                float zv = fmaf(r, acc[mi][ni][j] - m * s1r[ni], s2r[ni]);
                op[ewave + ni * 16 + l15] = zv;
            }
        }
    }
}

// ---------------------------------------------------------------------------
extern "C" void kernel_launch(void* const* d_in, const int* in_sizes, int n_in,
                              void* d_out, int out_size, void* d_ws, size_t ws_size,
                              hipStream_t stream)
{
    const float* x      = (const float*)d_in[0];
    const float* gamma  = (const float*)d_in[1];
    const float* beta   = (const float*)d_in[2];
    const float* v      = (const float*)d_in[3];
    const float* g      = (const float*)d_in[4];
    const float* bias   = (const float*)d_in[5];
    const int*   bstart = (const int*)d_in[6];
    const int*   bwidth = (const int*)d_in[7];
    float* out = (float*)d_out;

    unsigned short* ATg = (unsigned short*)d_ws;                 // 37*9*128*32 bf16
    float* s1  = (float*)(ATg + (size_t)NB * CHS * EE * 32);     // 37*128 f32
    float* s2p = s1 + NB * EE;                                   // 37*128 f32

    prep_kernel<<<NB * 16, 256, 0, stream>>>(gamma, beta, v, g, bias, bwidth, ATg, s1, s2p);
    fused_kernel<<<BB * NB * 16, 256, 0, stream>>>(x, bstart, bwidth, ATg, s1, s2p, out);
}